// Round 6
// baseline (274.931 us; speedup 1.0000x reference)
//
#include <hip/hip_runtime.h>

typedef short short8 __attribute__((ext_vector_type(8)));
typedef float f32x4 __attribute__((ext_vector_type(4)));
typedef float f32x16 __attribute__((ext_vector_type(16)));

constexpr int NROW  = 4096;
constexpr int DIN   = 1024;
constexpr int DPROJ = 1024;
constexpr float INV_DK = 0.17677669529663687f;  // 1/sqrt(32)

__device__ __forceinline__ unsigned short f2bf(float f) {
  union { float f; unsigned int u; } v; v.f = f;
  unsigned int r = v.u + 0x7FFFu + ((v.u >> 16) & 1u);
  return (unsigned short)(r >> 16);
}
__device__ __forceinline__ float bf2f(unsigned short h) {
  union { unsigned int u; float f; } v; v.u = ((unsigned int)h) << 16; return v.f;
}

// ---------------------------------------------------------------------------
// 128-row staging for the 128^2 kernels (unchanged).
// ---------------------------------------------------------------------------
template<int KB>
__device__ __forceinline__ void stage_tile(const unsigned short* __restrict__ g,
                                           long row0, long ldK, long k0,
                                           unsigned short* lds_tile, int w, int lane) {
  if constexpr (KB == 64) {
    const int rsub = lane >> 3;
    const int csw  = ((lane & 7) ^ (rsub & 7)) * 8;
#pragma unroll
    for (int it = 0; it < 4; ++it) {
      const int rowblk = w * 32 + it * 8;
      const unsigned short* src = g + (row0 + rowblk + rsub) * ldK + k0 + csw;
      unsigned short* dst = lds_tile + rowblk * 64;
      __builtin_amdgcn_global_load_lds(
          (const __attribute__((address_space(1))) unsigned int*)(const void*)src,
          (__attribute__((address_space(3))) unsigned int*)(void*)dst, 16, 0, 0);
    }
  } else {
    const int rsub = lane >> 2;
    const int csw  = ((lane & 3) ^ ((rsub >> 1) & 3)) * 8;
#pragma unroll
    for (int it = 0; it < 2; ++it) {
      const int rowblk = w * 32 + it * 16;
      const unsigned short* src = g + (row0 + rowblk + rsub) * ldK + k0 + csw;
      unsigned short* dst = lds_tile + rowblk * 32;
      __builtin_amdgcn_global_load_lds(
          (const __attribute__((address_space(1))) unsigned int*)(const void*)src,
          (__attribute__((address_space(3))) unsigned int*)(void*)dst, 16, 0, 0);
    }
  }
}

// ---------------------------------------------------------------------------
// 128^2 2-phase kernel (unchanged): V-proj, Q/K-proj, PV.
// ---------------------------------------------------------------------------
template<int SPLIT, int EPI, int KB>
__global__ __launch_bounds__(256, 2) void mfma_gemm(
    const unsigned short* __restrict__ Ah, const unsigned short* __restrict__ Al,
    const unsigned short* __restrict__ Bh, const unsigned short* __restrict__ Bl,
    const float* __restrict__ bias, float* __restrict__ Cf,
    unsigned short* __restrict__ Coh, unsigned short* __restrict__ Col,
    int M, int N, int K, float alpha)
{
  constexpr int NT = SPLIT ? 4 : 2;
  constexpr int TS = 128 * KB;
  __shared__ __align__(16) unsigned short lds[2][NT * TS];
  const int tid  = threadIdx.x;
  const int w    = tid >> 6, lane = tid & 63;
  const int wr   = w >> 1,   wc   = w & 1;
  const int lrow = lane & 15, lgrp = lane >> 4;
  const long bm = (long)blockIdx.y * 128, bn = (long)blockIdx.x * 128;

  f32x4 acc[4][4] = {};
  const int nsteps = K / KB;

  stage_tile<KB>(Ah, bm, K, 0, &lds[0][0 * TS], w, lane);
  stage_tile<KB>(Bh, bn, K, 0, &lds[0][1 * TS], w, lane);
  if constexpr (SPLIT) {
    stage_tile<KB>(Al, bm, K, 0, &lds[0][2 * TS], w, lane);
    stage_tile<KB>(Bl, bn, K, 0, &lds[0][3 * TS], w, lane);
  }

  int cur = 0;
  for (int t = 0; t < nsteps; ++t) {
    __syncthreads();
    if (t + 1 < nsteps) {
      const long k0 = (long)(t + 1) * KB;
      const int nb = cur ^ 1;
      stage_tile<KB>(Ah, bm, K, k0, &lds[nb][0 * TS], w, lane);
      stage_tile<KB>(Bh, bn, K, k0, &lds[nb][1 * TS], w, lane);
      if constexpr (SPLIT) {
        stage_tile<KB>(Al, bm, K, k0, &lds[nb][2 * TS], w, lane);
        stage_tile<KB>(Bl, bn, K, k0, &lds[nb][3 * TS], w, lane);
      }
    }
    const unsigned short* L = lds[cur];
#pragma unroll
    for (int s = 0; s < KB / 32; ++s) {
      short8 ah[4], bh[4], al[4], bl[4];
#pragma unroll
      for (int i = 0; i < 4; ++i) {
        const int ra  = wr * 64 + i * 16 + lrow;
        const int sga = (KB == 64) ? (ra & 7) : ((ra >> 1) & 3);
        const int offa = ra * KB + ((s * 4 + lgrp) ^ sga) * 8;
        ah[i] = *(const short8*)&L[0 * TS + offa];
        if constexpr (SPLIT) al[i] = *(const short8*)&L[2 * TS + offa];
        const int rb  = wc * 64 + i * 16 + lrow;
        const int sgb = (KB == 64) ? (rb & 7) : ((rb >> 1) & 3);
        const int offb = rb * KB + ((s * 4 + lgrp) ^ sgb) * 8;
        bh[i] = *(const short8*)&L[1 * TS + offb];
        if constexpr (SPLIT) bl[i] = *(const short8*)&L[3 * TS + offb];
      }
#pragma unroll
      for (int i = 0; i < 4; ++i)
#pragma unroll
        for (int j = 0; j < 4; ++j) {
          acc[i][j] = __builtin_amdgcn_mfma_f32_16x16x32_bf16(ah[i], bh[j], acc[i][j], 0, 0, 0);
          if constexpr (SPLIT) {
            acc[i][j] = __builtin_amdgcn_mfma_f32_16x16x32_bf16(ah[i], bl[j], acc[i][j], 0, 0, 0);
            acc[i][j] = __builtin_amdgcn_mfma_f32_16x16x32_bf16(al[i], bh[j], acc[i][j], 0, 0, 0);
          }
        }
    }
    cur ^= 1;
  }

#pragma unroll
  for (int i = 0; i < 4; ++i) {
    const long rbase = bm + wr * 64 + i * 16 + lgrp * 4;
#pragma unroll
    for (int j = 0; j < 4; ++j) {
      const long cg = bn + wc * 64 + j * 16 + lrow;
#pragma unroll
      for (int r = 0; r < 4; ++r) {
        const long rg = rbase + r;
        float v = acc[i][j][r];
        if constexpr (EPI == 0) {
          Cf[rg * N + cg] = alpha * v;
        } else if constexpr (EPI == 1) {
          v += bias[cg];
          unsigned short h = f2bf(v);
          Coh[rg * N + cg] = h;
          Col[rg * N + cg] = f2bf(v - bf2f(h));
        } else {
          v += bias[rg];
          Coh[rg * N + cg] = f2bf(v);
        }
      }
    }
  }
}

// ---------------------------------------------------------------------------
// 256^2 split-bf16 scores kernel, 32x32x16 MFMA, 2 k-slice phases per K-step.
// 512 threads = 8 waves (2M x 4N), wave tile 128x64 (4x2 tiles of 32x32).
// Every LDS byte read exactly once per K-step (24 ds_read_b128/wave).
// Counted vmcnt(8): prefetch loads never drained inside the loop.
// ---------------------------------------------------------------------------
__device__ __forceinline__ void stage256(const unsigned short* __restrict__ g,
    long row0, long ldK, long k0, unsigned short* tile, int w, int lane, int rnd)
{
  const int row_in = rnd * 128 + w * 16 + (lane >> 2);
  const int csw = ((lane & 3) ^ ((row_in >> 1) & 3)) * 8;
  const unsigned short* src = g + (row0 + row_in) * ldK + k0 + csw;
  unsigned short* dst = tile + (rnd * 128 + w * 16) * 32;   // wave-uniform base
  __builtin_amdgcn_global_load_lds(
      (const __attribute__((address_space(1))) unsigned int*)(const void*)src,
      (__attribute__((address_space(3))) unsigned int*)(void*)dst, 16, 0, 0);
}

__global__ __launch_bounds__(512, 2) void score_gemm256(
    const unsigned short* __restrict__ Ah, const unsigned short* __restrict__ Al,
    const unsigned short* __restrict__ Bh, const unsigned short* __restrict__ Bl,
    float* __restrict__ Cf, int M, int N, int K, float alpha)
{
  __shared__ __align__(16) unsigned short lds[2][4 * 8192];  // 128 KB
  const int tid  = threadIdx.x;
  const int w    = tid >> 6, lane = tid & 63;
  const int wr   = w >> 2,   wc   = w & 3;        // 2M x 4N waves
  const int l31  = lane & 31, lhalf = lane >> 5;  // row-in-tile, k-half
  const long bm = (long)blockIdx.y * 256, bn = (long)blockIdx.x * 256;

  f32x16 acc[4][2] = {};   // 4 m-tiles x 2 n-tiles of 32x32
  const int nsteps = K >> 5;   // BK = 32

  // Prologue: stage K-step 0 into buffer 0 (8 gloads).
#pragma unroll
  for (int r = 0; r < 2; ++r) {
    stage256(Ah, bm, K, 0, &lds[0][0 * 8192], w, lane, r);
    stage256(Al, bm, K, 0, &lds[0][1 * 8192], w, lane, r);
    stage256(Bh, bn, K, 0, &lds[0][2 * 8192], w, lane, r);
    stage256(Bl, bn, K, 0, &lds[0][3 * 8192], w, lane, r);
  }

  int cur = 0;
  for (int t = 0; t < nsteps; ++t) {
    const unsigned short* L = &lds[cur][0];
    unsigned short* Ln = &lds[cur ^ 1][0];
    const long kn = (long)(t + 1) << 5;
    const bool pf = (t + 1 < nsteps);

    // Phase-0 entry barrier: all waves have lgkm-completed their reads of
    // buf[cur^1] (last touched at previous step's phase 1), so the prefetch
    // below may overwrite it.
    __builtin_amdgcn_s_barrier();
    if (pf) {
#pragma unroll
      for (int r = 0; r < 2; ++r) {
        stage256(Ah, bm, K, kn, Ln + 0 * 8192, w, lane, r);
        stage256(Al, bm, K, kn, Ln + 1 * 8192, w, lane, r);
        stage256(Bh, bn, K, kn, Ln + 2 * 8192, w, lane, r);
        stage256(Bl, bn, K, kn, Ln + 3 * 8192, w, lane, r);
      }
      // Counted wait: exactly the 8 loads for buf[cur] (issued last step)
      // must land; the 8 just-issued stay in flight across both phases.
      asm volatile("s_waitcnt vmcnt(8)" ::: "memory");
    } else {
      asm volatile("s_waitcnt vmcnt(0)" ::: "memory");
    }
    __builtin_amdgcn_sched_barrier(0);

#pragma unroll
    for (int s = 0; s < 2; ++s) {
      if (s == 1) __builtin_amdgcn_s_barrier();   // phase alignment
      short8 a_h[4], a_l[4], b_h[2], b_l[2];
      const int chunk = s * 2 + lhalf;            // 8-elem k-chunk index
#pragma unroll
      for (int i = 0; i < 4; ++i) {
        const int ra = wr * 128 + i * 32 + l31;
        const int offa = ra * 32 + ((chunk ^ ((ra >> 1) & 3)) * 8);
        a_h[i] = *(const short8*)&L[0 * 8192 + offa];
        a_l[i] = *(const short8*)&L[1 * 8192 + offa];
      }
#pragma unroll
      for (int j = 0; j < 2; ++j) {
        const int rb = wc * 64 + j * 32 + l31;
        const int offb = rb * 32 + ((chunk ^ ((rb >> 1) & 3)) * 8);
        b_h[j] = *(const short8*)&L[2 * 8192 + offb];
        b_l[j] = *(const short8*)&L[3 * 8192 + offb];
      }
      __builtin_amdgcn_s_setprio(1);
#pragma unroll
      for (int i = 0; i < 4; ++i)
#pragma unroll
        for (int j = 0; j < 2; ++j) {
          acc[i][j] = __builtin_amdgcn_mfma_f32_32x32x16_bf16(a_h[i], b_h[j], acc[i][j], 0, 0, 0);
          acc[i][j] = __builtin_amdgcn_mfma_f32_32x32x16_bf16(a_h[i], b_l[j], acc[i][j], 0, 0, 0);
          acc[i][j] = __builtin_amdgcn_mfma_f32_32x32x16_bf16(a_l[i], b_h[j], acc[i][j], 0, 0, 0);
        }
      __builtin_amdgcn_s_setprio(0);
    }
    cur ^= 1;
  }

  // Epilogue. 32x32 C/D layout: col = lane&31, row = (reg&3)+8*(reg>>2)+4*(lane>>5).
#pragma unroll
  for (int i = 0; i < 4; ++i) {
#pragma unroll
    for (int j = 0; j < 2; ++j) {
      const long cg = bn + wc * 64 + j * 32 + l31;
#pragma unroll
      for (int reg = 0; reg < 16; ++reg) {
        const long rg = bm + wr * 128 + i * 32 + (reg & 3) + 8 * (reg >> 2) + 4 * lhalf;
        Cf[rg * (long)N + cg] = alpha * acc[i][j][reg];
      }
    }
  }
}

// f32 -> (hi, lo) bf16, same layout
__global__ __launch_bounds__(256) void split_rows(const float* __restrict__ in,
    unsigned short* __restrict__ oh, unsigned short* __restrict__ ol, int n4)
{
  int idx = blockIdx.x * 256 + threadIdx.x;
  const int stride = gridDim.x * 256;
  for (; idx < n4; idx += stride) {
    float4 v = ((const float4*)in)[idx];
    ushort4 h, l;
    h.x = f2bf(v.x); l.x = f2bf(v.x - bf2f(h.x));
    h.y = f2bf(v.y); l.y = f2bf(v.y - bf2f(h.y));
    h.z = f2bf(v.z); l.z = f2bf(v.z - bf2f(h.z));
    h.w = f2bf(v.w); l.w = f2bf(v.w - bf2f(h.w));
    ((ushort4*)oh)[idx] = h;
    ((ushort4*)ol)[idx] = l;
  }
}

// W (R x C f32) -> W^T hi/lo bf16 (C x R)
__global__ __launch_bounds__(256) void split_transpose(const float* __restrict__ W,
    unsigned short* __restrict__ oTh, unsigned short* __restrict__ oTl, int R, int C)
{
  __shared__ float t[64][65];
  const int rt = blockIdx.y * 64, ct = blockIdx.x * 64;
  const int r0 = threadIdx.x >> 4, c4 = (threadIdx.x & 15) * 4;
#pragma unroll
  for (int rr = 0; rr < 4; ++rr) {
    const int row = r0 + rr * 16;
    float4 v = *(const float4*)(W + (long)(rt + row) * C + ct + c4);
    t[row][c4 + 0] = v.x; t[row][c4 + 1] = v.y;
    t[row][c4 + 2] = v.z; t[row][c4 + 3] = v.w;
  }
  __syncthreads();
#pragma unroll
  for (int rr = 0; rr < 4; ++rr) {
    const int orow = r0 + rr * 16;
    float x0 = t[c4 + 0][orow], x1 = t[c4 + 1][orow];
    float x2 = t[c4 + 2][orow], x3 = t[c4 + 3][orow];
    ushort4 h, l;
    h.x = f2bf(x0); l.x = f2bf(x0 - bf2f(h.x));
    h.y = f2bf(x1); l.y = f2bf(x1 - bf2f(h.y));
    h.z = f2bf(x2); l.z = f2bf(x2 - bf2f(h.z));
    h.w = f2bf(x3); l.w = f2bf(x3 - bf2f(h.w));
    *(ushort4*)(oTh + (long)(ct + orow) * R + rt + c4) = h;
    *(ushort4*)(oTl + (long)(ct + orow) * R + rt + c4) = l;
  }
}

// In-place row softmax over 4096 cols + bf16 copy of the normalized row.
__global__ __launch_bounds__(256) void softmax_p(float* __restrict__ S,
                                                 unsigned short* __restrict__ P)
{
  const int tid = threadIdx.x;
  float* p = S + (size_t)blockIdx.x * 4096;
  unsigned short* pb = P + (size_t)blockIdx.x * 4096;
  float4 v[4];
  float mx = -3.402823466e38f;
#pragma unroll
  for (int i = 0; i < 4; ++i) {
    v[i] = *(const float4*)(p + 4 * (tid + i * 256));
    mx = fmaxf(mx, fmaxf(fmaxf(v[i].x, v[i].y), fmaxf(v[i].z, v[i].w)));
  }
#pragma unroll
  for (int off = 32; off >= 1; off >>= 1) mx = fmaxf(mx, __shfl_xor(mx, off));
  __shared__ float redm[4], reds[4];
  if ((tid & 63) == 0) redm[tid >> 6] = mx;
  __syncthreads();
  mx = fmaxf(fmaxf(redm[0], redm[1]), fmaxf(redm[2], redm[3]));

  float sum = 0.f;
#pragma unroll
  for (int i = 0; i < 4; ++i) {
    v[i].x = __expf(v[i].x - mx); v[i].y = __expf(v[i].y - mx);
    v[i].z = __expf(v[i].z - mx); v[i].w = __expf(v[i].w - mx);
    sum += (v[i].x + v[i].y) + (v[i].z + v[i].w);
  }
#pragma unroll
  for (int off = 32; off >= 1; off >>= 1) sum += __shfl_xor(sum, off);
  if ((tid & 63) == 0) reds[tid >> 6] = sum;
  __syncthreads();
  sum = (reds[0] + reds[1]) + (reds[2] + reds[3]);
  const float inv = 1.0f / sum;
#pragma unroll
  for (int i = 0; i < 4; ++i) {
    v[i].x *= inv; v[i].y *= inv; v[i].z *= inv; v[i].w *= inv;
    *(float4*)(p + 4 * (tid + i * 256)) = v[i];
    ushort4 h;
    h.x = f2bf(v[i].x); h.y = f2bf(v[i].y); h.z = f2bf(v[i].z); h.w = f2bf(v[i].w);
    *(ushort4*)(pb + 4 * (tid + i * 256)) = h;
  }
}

extern "C" void kernel_launch(void* const* d_in, const int* in_sizes, int n_in,
                              void* d_out, int out_size, void* d_ws, size_t ws_size,
                              hipStream_t stream)
{
  const float* x  = (const float*)d_in[0];
  const float* Wq = (const float*)d_in[1];
  const float* bq = (const float*)d_in[2];
  const float* Wk = (const float*)d_in[3];
  const float* bk = (const float*)d_in[4];
  const float* Wv = (const float*)d_in[5];
  const float* bv = (const float*)d_in[6];

  float* attn_out = (float*)d_out;                    // [4096,1024] f32
  float* attn_w   = attn_out + (size_t)NROW * DPROJ;  // [4096,4096] f32

  constexpr size_t MB = 1ull << 20;
  // Scratch inside the not-yet-written attn_w region (64 MB): dead before scores.
  char* sc = (char*)attn_w;
  unsigned short* xh   = (unsigned short*)(sc + 0 * MB);
  unsigned short* xl   = (unsigned short*)(sc + 8 * MB);
  unsigned short* WqTh = (unsigned short*)(sc + 16 * MB);
  unsigned short* WqTl = (unsigned short*)(sc + 18 * MB);
  unsigned short* WkTh = (unsigned short*)(sc + 20 * MB);
  unsigned short* WkTl = (unsigned short*)(sc + 22 * MB);
  unsigned short* WvTh = (unsigned short*)(sc + 24 * MB);
  unsigned short* WvTl = (unsigned short*)(sc + 26 * MB);
  // Workspace (peak 40 MB): VT + Q/K splits; P aliases dead Q/K region.
  char* wsb = (char*)d_ws;
  unsigned short* VT = (unsigned short*)(wsb + 0 * MB);
  unsigned short* Qh = (unsigned short*)(wsb + 8 * MB);
  unsigned short* Ql = (unsigned short*)(wsb + 16 * MB);
  unsigned short* Kh = (unsigned short*)(wsb + 24 * MB);
  unsigned short* Kl = (unsigned short*)(wsb + 32 * MB);
  unsigned short* P  = (unsigned short*)(wsb + 8 * MB);

  dim3 blk(256);

  // 1) converts
  split_rows<<<4096, blk, 0, stream>>>(x, xh, xl, NROW * DIN / 4);
  dim3 gtr(16, 16);
  split_transpose<<<gtr, blk, 0, stream>>>(Wq, WqTh, WqTl, DIN, DPROJ);
  split_transpose<<<gtr, blk, 0, stream>>>(Wk, WkTh, WkTl, DIN, DPROJ);
  split_transpose<<<gtr, blk, 0, stream>>>(Wv, WvTh, WvTl, DIN, DPROJ);

  // 2) V^T = Wv^T @ x^T  (plain bf16)
  mfma_gemm<0, 3, 64><<<dim3(NROW / 128, DPROJ / 128), blk, 0, stream>>>(
      WvTh, nullptr, xh, nullptr, bv, nullptr, VT, nullptr,
      DPROJ, NROW, DIN, 1.0f);

  // 3) Q = x @ Wq + bq (split in, split-bf16 out)
  mfma_gemm<1, 1, 32><<<dim3(DPROJ / 128, NROW / 128), blk, 0, stream>>>(
      xh, xl, WqTh, WqTl, bq, nullptr, Qh, Ql, NROW, DPROJ, DIN, 1.0f);
  // 4) K = x @ Wk + bk
  mfma_gemm<1, 1, 32><<<dim3(DPROJ / 128, NROW / 128), blk, 0, stream>>>(
      xh, xl, WkTh, WkTl, bk, nullptr, Kh, Kl, NROW, DPROJ, DIN, 1.0f);

  // 5) scores = (Q @ K^T) / sqrt(32) -> attn_w f32 (256^2, 32x32x16)
  score_gemm256<<<dim3(NROW / 256, NROW / 256), dim3(512), 0, stream>>>(
      Qh, Ql, Kh, Kl, attn_w, NROW, NROW, DPROJ, INV_DK);

  // 6) softmax in place + P bf16
  softmax_p<<<NROW, blk, 0, stream>>>(attn_w, P);

  // 7) attn_out = P @ V
  mfma_gemm<0, 0, 64><<<dim3(DPROJ / 128, NROW / 128), blk, 0, stream>>>(
      P, nullptr, VT, nullptr, nullptr, attn_out, nullptr, nullptr,
      NROW, DPROJ, NROW, 1.0f);
}

// Round 7
// 238.368 us; speedup vs baseline: 1.1534x; 1.1534x over previous
//
#include <hip/hip_runtime.h>

typedef short short8 __attribute__((ext_vector_type(8)));
typedef float f32x4 __attribute__((ext_vector_type(4)));

constexpr int NROW  = 4096;
constexpr int DIN   = 1024;
constexpr int DPROJ = 1024;
constexpr float INV_DK = 0.17677669529663687f;  // 1/sqrt(32)

__device__ __forceinline__ unsigned short f2bf(float f) {
  union { float f; unsigned int u; } v; v.f = f;
  unsigned int r = v.u + 0x7FFFu + ((v.u >> 16) & 1u);
  return (unsigned short)(r >> 16);
}
__device__ __forceinline__ float bf2f(unsigned short h) {
  union { unsigned int u; float f; } v; v.u = ((unsigned int)h) << 16; return v.f;
}

// ---------------------------------------------------------------------------
// Stage one 128-row x KB-col bf16 tile into LDS via global_load_lds (16B),
// read-side XOR swizzle pre-applied to the GLOBAL source (linear LDS dest).
// ---------------------------------------------------------------------------
template<int KB>
__device__ __forceinline__ void stage_tile(const unsigned short* __restrict__ g,
                                           long row0, long ldK, long k0,
                                           unsigned short* lds_tile, int w, int lane) {
  if constexpr (KB == 64) {
    const int rsub = lane >> 3;
    const int csw  = ((lane & 7) ^ (rsub & 7)) * 8;
#pragma unroll
    for (int it = 0; it < 4; ++it) {
      const int rowblk = w * 32 + it * 8;
      const unsigned short* src = g + (row0 + rowblk + rsub) * ldK + k0 + csw;
      unsigned short* dst = lds_tile + rowblk * 64;
      __builtin_amdgcn_global_load_lds(
          (const __attribute__((address_space(1))) unsigned int*)(const void*)src,
          (__attribute__((address_space(3))) unsigned int*)(void*)dst, 16, 0, 0);
    }
  } else {
    const int rsub = lane >> 2;
    const int csw  = ((lane & 3) ^ ((rsub >> 1) & 3)) * 8;
#pragma unroll
    for (int it = 0; it < 2; ++it) {
      const int rowblk = w * 32 + it * 16;
      const unsigned short* src = g + (row0 + rowblk + rsub) * ldK + k0 + csw;
      unsigned short* dst = lds_tile + rowblk * 32;
      __builtin_amdgcn_global_load_lds(
          (const __attribute__((address_space(1))) unsigned int*)(const void*)src,
          (__attribute__((address_space(3))) unsigned int*)(void*)dst, 16, 0, 0);
    }
  }
}

// 64-row x 64-col tile (B operand of the n64 kernel): 2 gloads/wave.
__device__ __forceinline__ void stage_tile64r(const unsigned short* __restrict__ g,
                                              long row0, long ldK, long k0,
                                              unsigned short* lds_tile, int w, int lane) {
  const int rsub = lane >> 3;
  const int csw  = ((lane & 7) ^ (rsub & 7)) * 8;
#pragma unroll
  for (int it = 0; it < 2; ++it) {
    const int rowblk = w * 16 + it * 8;
    const unsigned short* src = g + (row0 + rowblk + rsub) * ldK + k0 + csw;
    unsigned short* dst = lds_tile + rowblk * 64;
    __builtin_amdgcn_global_load_lds(
        (const __attribute__((address_space(1))) unsigned int*)(const void*)src,
        (__attribute__((address_space(3))) unsigned int*)(void*)dst, 16, 0, 0);
  }
}

// ---------------------------------------------------------------------------
// Merged Q+K projection: 512 blocks (2/CU). blockIdx.x>>8 selects Q or K.
// Split-bf16 3-term, KB=32, BM=BN=128, M=4096, N=K=1024, EPI=split-out+col-bias.
// ---------------------------------------------------------------------------
__global__ __launch_bounds__(256, 2) void qk_proj(
    const unsigned short* __restrict__ xh, const unsigned short* __restrict__ xl,
    const unsigned short* __restrict__ WqTh, const unsigned short* __restrict__ WqTl,
    const unsigned short* __restrict__ WkTh, const unsigned short* __restrict__ WkTl,
    const float* __restrict__ bq, const float* __restrict__ bk,
    unsigned short* __restrict__ Qh, unsigned short* __restrict__ Ql,
    unsigned short* __restrict__ Kh, unsigned short* __restrict__ Kl)
{
  constexpr int K = 1024, N = 1024, TS = 128 * 32;
  __shared__ __align__(16) unsigned short lds[2][4 * TS];  // 64 KB
  const int tid = threadIdx.x, w = tid >> 6, lane = tid & 63;
  const int wr = w >> 1, wc = w & 1, lrow = lane & 15, lgrp = lane >> 4;
  const int which = blockIdx.x >> 8;
  const int b = blockIdx.x & 255;
  const long bm = (long)(b >> 3) * 128;
  const long bn = (long)(b & 7) * 128;
  const unsigned short* Bh = which ? WkTh : WqTh;
  const unsigned short* Bl = which ? WkTl : WqTl;
  const float* bias = which ? bk : bq;
  unsigned short* Oh = which ? Kh : Qh;
  unsigned short* Ol = which ? Kl : Ql;

  f32x4 acc[4][4] = {};
  const int nsteps = K >> 5;

  stage_tile<32>(xh, bm, K, 0, &lds[0][0 * TS], w, lane);
  stage_tile<32>(Bh, bn, K, 0, &lds[0][1 * TS], w, lane);
  stage_tile<32>(xl, bm, K, 0, &lds[0][2 * TS], w, lane);
  stage_tile<32>(Bl, bn, K, 0, &lds[0][3 * TS], w, lane);

  int cur = 0;
  for (int t = 0; t < nsteps; ++t) {
    __syncthreads();
    if (t + 1 < nsteps) {
      const long k0 = (long)(t + 1) << 5;
      const int nb = cur ^ 1;
      stage_tile<32>(xh, bm, K, k0, &lds[nb][0 * TS], w, lane);
      stage_tile<32>(Bh, bn, K, k0, &lds[nb][1 * TS], w, lane);
      stage_tile<32>(xl, bm, K, k0, &lds[nb][2 * TS], w, lane);
      stage_tile<32>(Bl, bn, K, k0, &lds[nb][3 * TS], w, lane);
    }
    const unsigned short* L = lds[cur];
    short8 ah[4], bh[4], al[4], bl[4];
#pragma unroll
    for (int i = 0; i < 4; ++i) {
      const int ra = wr * 64 + i * 16 + lrow;
      const int offa = ra * 32 + ((lgrp ^ ((ra >> 1) & 3)) * 8);
      ah[i] = *(const short8*)&L[0 * TS + offa];
      al[i] = *(const short8*)&L[2 * TS + offa];
      const int rb = wc * 64 + i * 16 + lrow;
      const int offb = rb * 32 + ((lgrp ^ ((rb >> 1) & 3)) * 8);
      bh[i] = *(const short8*)&L[1 * TS + offb];
      bl[i] = *(const short8*)&L[3 * TS + offb];
    }
#pragma unroll
    for (int i = 0; i < 4; ++i)
#pragma unroll
      for (int j = 0; j < 4; ++j) {
        acc[i][j] = __builtin_amdgcn_mfma_f32_16x16x32_bf16(ah[i], bh[j], acc[i][j], 0, 0, 0);
        acc[i][j] = __builtin_amdgcn_mfma_f32_16x16x32_bf16(ah[i], bl[j], acc[i][j], 0, 0, 0);
        acc[i][j] = __builtin_amdgcn_mfma_f32_16x16x32_bf16(al[i], bh[j], acc[i][j], 0, 0, 0);
      }
    cur ^= 1;
  }

#pragma unroll
  for (int i = 0; i < 4; ++i) {
    const long rbase = bm + wr * 64 + i * 16 + lgrp * 4;
#pragma unroll
    for (int j = 0; j < 4; ++j) {
      const long cg = bn + wc * 64 + j * 16 + lrow;
#pragma unroll
      for (int r = 0; r < 4; ++r) {
        const long rg = rbase + r;
        float v = acc[i][j][r] + bias[cg];
        unsigned short h = f2bf(v);
        Oh[rg * N + cg] = h;
        Ol[rg * N + cg] = f2bf(v - bf2f(h));
      }
    }
  }
}

// ---------------------------------------------------------------------------
// Plain-bf16 BM=128 x BN=64 kernel (KB=64): doubles grid size for V-proj/PV
// so 512 blocks -> 2 blocks/CU (TLP restores latency hiding).
// EPI: 0 = f32 out; 3 = bf16 out + row bias.
// ---------------------------------------------------------------------------
template<int EPI>
__global__ __launch_bounds__(256, 2) void gemm_n64(
    const unsigned short* __restrict__ A, const unsigned short* __restrict__ B,
    const float* __restrict__ bias, float* __restrict__ Cf,
    unsigned short* __restrict__ Co, int M, int N, int K)
{
  constexpr int TSA = 128 * 64;            // A tile, ushorts
  constexpr int TSB = 64 * 64;             // B tile
  __shared__ __align__(16) unsigned short lds[2][TSA + TSB];  // 48 KB
  const int tid = threadIdx.x, w = tid >> 6, lane = tid & 63;
  const int wr = w >> 1, wc = w & 1, lrow = lane & 15, lgrp = lane >> 4;
  const long bm = (long)blockIdx.y * 128, bn = (long)blockIdx.x * 64;

  f32x4 acc[4][2] = {};
  const int nsteps = K >> 6;

  stage_tile<64>(A, bm, K, 0, &lds[0][0], w, lane);
  stage_tile64r(B, bn, K, 0, &lds[0][TSA], w, lane);

  int cur = 0;
  for (int t = 0; t < nsteps; ++t) {
    __syncthreads();
    if (t + 1 < nsteps) {
      const long k0 = (long)(t + 1) << 6;
      const int nb = cur ^ 1;
      stage_tile<64>(A, bm, K, k0, &lds[nb][0], w, lane);
      stage_tile64r(B, bn, K, k0, &lds[nb][TSA], w, lane);
    }
    const unsigned short* L = lds[cur];
#pragma unroll
    for (int s = 0; s < 2; ++s) {
      short8 a[4], bb[2];
#pragma unroll
      for (int i = 0; i < 4; ++i) {
        const int ra = wr * 64 + i * 16 + lrow;
        const int offa = ra * 64 + (((s * 4 + lgrp) ^ (ra & 7)) * 8);
        a[i] = *(const short8*)&L[offa];
      }
#pragma unroll
      for (int j = 0; j < 2; ++j) {
        const int rb = wc * 32 + j * 16 + lrow;
        const int offb = rb * 64 + (((s * 4 + lgrp) ^ (rb & 7)) * 8);
        bb[j] = *(const short8*)&L[TSA + offb];
      }
#pragma unroll
      for (int i = 0; i < 4; ++i)
#pragma unroll
        for (int j = 0; j < 2; ++j)
          acc[i][j] = __builtin_amdgcn_mfma_f32_16x16x32_bf16(a[i], bb[j], acc[i][j], 0, 0, 0);
    }
    cur ^= 1;
  }

#pragma unroll
  for (int i = 0; i < 4; ++i) {
    const long rbase = bm + wr * 64 + i * 16 + lgrp * 4;
#pragma unroll
    for (int j = 0; j < 2; ++j) {
      const long cg = bn + wc * 32 + j * 16 + lrow;
#pragma unroll
      for (int r = 0; r < 4; ++r) {
        const long rg = rbase + r;
        if constexpr (EPI == 0) {
          Cf[rg * (long)N + cg] = acc[i][j][r];
        } else {
          Co[rg * (long)N + cg] = f2bf(acc[i][j][r] + bias[rg]);
        }
      }
    }
  }
}

// ---------------------------------------------------------------------------
// 256^2 split-bf16 scores kernel (R5 version: 16x16 MFMA, 4 quadrant phases,
// counted vmcnt, 0 bank conflicts, ~97 us / 44% MfmaUtil).
// ---------------------------------------------------------------------------
__device__ __forceinline__ void stage256(const unsigned short* __restrict__ g,
    long row0, long ldK, long k0, unsigned short* tile, int w, int lane, int rnd)
{
  const int row_in = rnd * 128 + w * 16 + (lane >> 2);
  const int csw = ((lane & 3) ^ ((row_in >> 1) & 3)) * 8;
  const unsigned short* src = g + (row0 + row_in) * ldK + k0 + csw;
  unsigned short* dst = tile + (rnd * 128 + w * 16) * 32;   // wave-uniform base
  __builtin_amdgcn_global_load_lds(
      (const __attribute__((address_space(1))) unsigned int*)(const void*)src,
      (__attribute__((address_space(3))) unsigned int*)(void*)dst, 16, 0, 0);
}

__global__ __launch_bounds__(512, 2) void score_gemm256(
    const unsigned short* __restrict__ Ah, const unsigned short* __restrict__ Al,
    const unsigned short* __restrict__ Bh, const unsigned short* __restrict__ Bl,
    float* __restrict__ Cf, int M, int N, int K, float alpha)
{
  __shared__ __align__(16) unsigned short lds[2][4 * 8192];  // 128 KB
  const int tid  = threadIdx.x;
  const int w    = tid >> 6, lane = tid & 63;
  const int wr   = w >> 2,   wc   = w & 3;       // 2M x 4N
  const int lrow = lane & 15, lgrp = lane >> 4;
  const long bm = (long)blockIdx.y * 256, bn = (long)blockIdx.x * 256;

  f32x4 acc[8][4] = {};
  const int nsteps = K >> 5;   // BK = 32

  {
    unsigned short* B0 = &lds[0][0];
#pragma unroll
    for (int r = 0; r < 2; ++r) {
      stage256(Ah, bm, K, 0, B0 + 0 * 8192, w, lane, r);
      stage256(Al, bm, K, 0, B0 + 1 * 8192, w, lane, r);
      stage256(Bh, bn, K, 0, B0 + 2 * 8192, w, lane, r);
      stage256(Bl, bn, K, 0, B0 + 3 * 8192, w, lane, r);
    }
  }
  asm volatile("s_waitcnt vmcnt(0)" ::: "memory");

  int cur = 0;
  for (int t = 0; t < nsteps; ++t) {
    const unsigned short* L = &lds[cur][0];
    unsigned short* Ln = &lds[cur ^ 1][0];
    const long kn = (long)(t + 1) << 5;
    const bool pf = (t + 1 < nsteps);
#pragma unroll
    for (int q = 0; q < 4; ++q) {
      __builtin_amdgcn_s_barrier();          // phase entry (raw, no vmem drain)
      __builtin_amdgcn_sched_barrier(0);
      const int mh = q >> 1, nh = q & 1;
      short8 a_h[4], a_l[4], b_h[2], b_l[2];
#pragma unroll
      for (int i = 0; i < 4; ++i) {
        const int ra = wr * 128 + mh * 64 + i * 16 + lrow;
        const int offa = ra * 32 + ((lgrp ^ ((ra >> 1) & 3)) * 8);
        a_h[i] = *(const short8*)&L[0 * 8192 + offa];
        a_l[i] = *(const short8*)&L[1 * 8192 + offa];
      }
#pragma unroll
      for (int j = 0; j < 2; ++j) {
        const int rb = wc * 64 + nh * 32 + j * 16 + lrow;
        const int offb = rb * 32 + ((lgrp ^ ((rb >> 1) & 3)) * 8);
        b_h[j] = *(const short8*)&L[2 * 8192 + offb];
        b_l[j] = *(const short8*)&L[3 * 8192 + offb];
      }
      if (pf && q == 0) {
#pragma unroll
        for (int r = 0; r < 2; ++r) {
          stage256(Ah, bm, K, kn, Ln + 0 * 8192, w, lane, r);
          stage256(Bh, bn, K, kn, Ln + 2 * 8192, w, lane, r);
        }
      }
      if (pf && q == 1) {
#pragma unroll
        for (int r = 0; r < 2; ++r) {
          stage256(Al, bm, K, kn, Ln + 1 * 8192, w, lane, r);
          stage256(Bl, bn, K, kn, Ln + 3 * 8192, w, lane, r);
        }
      }
      __builtin_amdgcn_sched_barrier(0);
      __builtin_amdgcn_s_setprio(1);
#pragma unroll
      for (int i = 0; i < 4; ++i)
#pragma unroll
        for (int j = 0; j < 2; ++j) {
          const int ai = mh * 4 + i, aj = nh * 2 + j;
          acc[ai][aj] = __builtin_amdgcn_mfma_f32_16x16x32_bf16(a_h[i], b_h[j], acc[ai][aj], 0, 0, 0);
          acc[ai][aj] = __builtin_amdgcn_mfma_f32_16x16x32_bf16(a_h[i], b_l[j], acc[ai][aj], 0, 0, 0);
          acc[ai][aj] = __builtin_amdgcn_mfma_f32_16x16x32_bf16(a_l[i], b_h[j], acc[ai][aj], 0, 0, 0);
        }
      __builtin_amdgcn_s_setprio(0);
      if (q == 3) {
        asm volatile("s_waitcnt vmcnt(0)" ::: "memory");
        __builtin_amdgcn_sched_barrier(0);
      }
    }
    cur ^= 1;
  }

#pragma unroll
  for (int i = 0; i < 8; ++i) {
    const long rbase = bm + wr * 128 + i * 16 + lgrp * 4;
#pragma unroll
    for (int j = 0; j < 4; ++j) {
      const long cg = bn + wc * 64 + j * 16 + lrow;
#pragma unroll
      for (int r = 0; r < 4; ++r)
        Cf[(rbase + r) * (long)N + cg] = alpha * acc[i][j][r];
    }
  }
}

// f32 -> (hi, lo) bf16, same layout
__global__ __launch_bounds__(256) void split_rows(const float* __restrict__ in,
    unsigned short* __restrict__ oh, unsigned short* __restrict__ ol, int n4)
{
  int idx = blockIdx.x * 256 + threadIdx.x;
  const int stride = gridDim.x * 256;
  for (; idx < n4; idx += stride) {
    float4 v = ((const float4*)in)[idx];
    ushort4 h, l;
    h.x = f2bf(v.x); l.x = f2bf(v.x - bf2f(h.x));
    h.y = f2bf(v.y); l.y = f2bf(v.y - bf2f(h.y));
    h.z = f2bf(v.z); l.z = f2bf(v.z - bf2f(h.z));
    h.w = f2bf(v.w); l.w = f2bf(v.w - bf2f(h.w));
    ((ushort4*)oh)[idx] = h;
    ((ushort4*)ol)[idx] = l;
  }
}

// W (R x C f32) -> W^T hi/lo bf16 (C x R)
__global__ __launch_bounds__(256) void split_transpose(const float* __restrict__ W,
    unsigned short* __restrict__ oTh, unsigned short* __restrict__ oTl, int R, int C)
{
  __shared__ float t[64][65];
  const int rt = blockIdx.y * 64, ct = blockIdx.x * 64;
  const int r0 = threadIdx.x >> 4, c4 = (threadIdx.x & 15) * 4;
#pragma unroll
  for (int rr = 0; rr < 4; ++rr) {
    const int row = r0 + rr * 16;
    float4 v = *(const float4*)(W + (long)(rt + row) * C + ct + c4);
    t[row][c4 + 0] = v.x; t[row][c4 + 1] = v.y;
    t[row][c4 + 2] = v.z; t[row][c4 + 3] = v.w;
  }
  __syncthreads();
#pragma unroll
  for (int rr = 0; rr < 4; ++rr) {
    const int orow = r0 + rr * 16;
    float x0 = t[c4 + 0][orow], x1 = t[c4 + 1][orow];
    float x2 = t[c4 + 2][orow], x3 = t[c4 + 3][orow];
    ushort4 h, l;
    h.x = f2bf(x0); l.x = f2bf(x0 - bf2f(h.x));
    h.y = f2bf(x1); l.y = f2bf(x1 - bf2f(h.y));
    h.z = f2bf(x2); l.z = f2bf(x2 - bf2f(h.z));
    h.w = f2bf(x3); l.w = f2bf(x3 - bf2f(h.w));
    *(ushort4*)(oTh + (long)(ct + orow) * R + rt + c4) = h;
    *(ushort4*)(oTl + (long)(ct + orow) * R + rt + c4) = l;
  }
}

// In-place row softmax over 4096 cols + bf16 copy of the normalized row.
__global__ __launch_bounds__(256) void softmax_p(float* __restrict__ S,
                                                 unsigned short* __restrict__ P)
{
  const int tid = threadIdx.x;
  float* p = S + (size_t)blockIdx.x * 4096;
  unsigned short* pb = P + (size_t)blockIdx.x * 4096;
  float4 v[4];
  float mx = -3.402823466e38f;
#pragma unroll
  for (int i = 0; i < 4; ++i) {
    v[i] = *(const float4*)(p + 4 * (tid + i * 256));
    mx = fmaxf(mx, fmaxf(fmaxf(v[i].x, v[i].y), fmaxf(v[i].z, v[i].w)));
  }
#pragma unroll
  for (int off = 32; off >= 1; off >>= 1) mx = fmaxf(mx, __shfl_xor(mx, off));
  __shared__ float redm[4], reds[4];
  if ((tid & 63) == 0) redm[tid >> 6] = mx;
  __syncthreads();
  mx = fmaxf(fmaxf(redm[0], redm[1]), fmaxf(redm[2], redm[3]));

  float sum = 0.f;
#pragma unroll
  for (int i = 0; i < 4; ++i) {
    v[i].x = __expf(v[i].x - mx); v[i].y = __expf(v[i].y - mx);
    v[i].z = __expf(v[i].z - mx); v[i].w = __expf(v[i].w - mx);
    sum += (v[i].x + v[i].y) + (v[i].z + v[i].w);
  }
#pragma unroll
  for (int off = 32; off >= 1; off >>= 1) sum += __shfl_xor(sum, off);
  if ((tid & 63) == 0) reds[tid >> 6] = sum;
  __syncthreads();
  sum = (reds[0] + reds[1]) + (reds[2] + reds[3]);
  const float inv = 1.0f / sum;
#pragma unroll
  for (int i = 0; i < 4; ++i) {
    v[i].x *= inv; v[i].y *= inv; v[i].z *= inv; v[i].w *= inv;
    *(float4*)(p + 4 * (tid + i * 256)) = v[i];
    ushort4 h;
    h.x = f2bf(v[i].x); h.y = f2bf(v[i].y); h.z = f2bf(v[i].z); h.w = f2bf(v[i].w);
    *(ushort4*)(pb + 4 * (tid + i * 256)) = h;
  }
}

extern "C" void kernel_launch(void* const* d_in, const int* in_sizes, int n_in,
                              void* d_out, int out_size, void* d_ws, size_t ws_size,
                              hipStream_t stream)
{
  const float* x  = (const float*)d_in[0];
  const float* Wq = (const float*)d_in[1];
  const float* bq = (const float*)d_in[2];
  const float* Wk = (const float*)d_in[3];
  const float* bk = (const float*)d_in[4];
  const float* Wv = (const float*)d_in[5];
  const float* bv = (const float*)d_in[6];

  float* attn_out = (float*)d_out;                    // [4096,1024] f32
  float* attn_w   = attn_out + (size_t)NROW * DPROJ;  // [4096,4096] f32

  constexpr size_t MB = 1ull << 20;
  // Scratch inside the not-yet-written attn_w region (64 MB): dead before scores.
  char* sc = (char*)attn_w;
  unsigned short* xh   = (unsigned short*)(sc + 0 * MB);
  unsigned short* xl   = (unsigned short*)(sc + 8 * MB);
  unsigned short* WqTh = (unsigned short*)(sc + 16 * MB);
  unsigned short* WqTl = (unsigned short*)(sc + 18 * MB);
  unsigned short* WkTh = (unsigned short*)(sc + 20 * MB);
  unsigned short* WkTl = (unsigned short*)(sc + 22 * MB);
  unsigned short* WvTh = (unsigned short*)(sc + 24 * MB);
  unsigned short* WvTl = (unsigned short*)(sc + 26 * MB);  // unused
  // Workspace (peak 40 MB): VT + Q/K splits; P aliases dead Q/K region.
  char* wsb = (char*)d_ws;
  unsigned short* VT = (unsigned short*)(wsb + 0 * MB);
  unsigned short* Qh = (unsigned short*)(wsb + 8 * MB);
  unsigned short* Ql = (unsigned short*)(wsb + 16 * MB);
  unsigned short* Kh = (unsigned short*)(wsb + 24 * MB);
  unsigned short* Kl = (unsigned short*)(wsb + 32 * MB);
  unsigned short* P  = (unsigned short*)(wsb + 8 * MB);

  dim3 blk(256);

  // 1) converts
  split_rows<<<4096, blk, 0, stream>>>(x, xh, xl, NROW * DIN / 4);
  dim3 gtr(16, 16);
  split_transpose<<<gtr, blk, 0, stream>>>(Wq, WqTh, WqTl, DIN, DPROJ);
  split_transpose<<<gtr, blk, 0, stream>>>(Wk, WkTh, WkTl, DIN, DPROJ);
  split_transpose<<<gtr, blk, 0, stream>>>(Wv, WvTh, WvTl, DIN, DPROJ);

  // 2) V^T = Wv^T @ x^T (plain bf16), 512 blocks (2/CU)
  gemm_n64<3><<<dim3(NROW / 64, DPROJ / 128), blk, 0, stream>>>(
      WvTh, xh, bv, nullptr, VT, DPROJ, NROW, DIN);

  // 3+4) Q and K projections merged: 512 blocks (2/CU)
  qk_proj<<<512, blk, 0, stream>>>(xh, xl, WqTh, WqTl, WkTh, WkTl,
                                   bq, bk, Qh, Ql, Kh, Kl);

  // 5) scores = (Q @ K^T) / sqrt(32) -> attn_w f32
  score_gemm256<<<dim3(NROW / 256, NROW / 256), dim3(512), 0, stream>>>(
      Qh, Ql, Kh, Kl, attn_w, NROW, NROW, DPROJ, INV_DK);

  // 6) softmax in place + P bf16
  softmax_p<<<NROW, blk, 0, stream>>>(attn_w, P);

  // 7) attn_out = P @ V, 512 blocks (2/CU)
  gemm_n64<0><<<dim3(DPROJ / 64, NROW / 128), blk, 0, stream>>>(
      P, VT, nullptr, attn_out, nullptr, NROW, DPROJ, NROW);
}